// Round 5
// baseline (534.847 us; speedup 1.0000x reference)
//
#include <hip/hip_runtime.h>
#include <cstdint>

#define T_TOKENS 4096
#define HDIM 2048
#define IDIM 1024
#define NEXP 8
#define NTOT 12
#define MAX_SLOTS 8320   // 8192 + 128 pad for tile overshoot reads

typedef __bf16 bf16x8_t __attribute__((ext_vector_type(8)));
typedef float f32x4_t __attribute__((ext_vector_type(4)));
typedef unsigned short u16x8_t __attribute__((ext_vector_type(8)));
typedef unsigned int u32x4_t __attribute__((ext_vector_type(4)));

__device__ __forceinline__ unsigned short f2bf(float f) {
    unsigned int u = __builtin_bit_cast(unsigned int, f);
    u += 0x7fffu + ((u >> 16) & 1u);
    return (unsigned short)(u >> 16);
}
__device__ __forceinline__ float bfu2f(unsigned short u) {
    unsigned int v = ((unsigned int)u) << 16;
    return __builtin_bit_cast(float, v);
}
__device__ __forceinline__ unsigned int pk2(float a, float b) {
    return (unsigned int)f2bf(a) | ((unsigned int)f2bf(b) << 16);
}
// pack 8 fp32 (2x f32x4) -> 8 bf16, one ds_write_b128
__device__ __forceinline__ void pack8(f32x4_t f0, f32x4_t f1, unsigned short* dst) {
    u32x4_t v;
    v[0] = pk2(f0[0], f0[1]);
    v[1] = pk2(f0[2], f0[3]);
    v[2] = pk2(f1[0], f1[1]);
    v[3] = pk2(f1[2], f1[3]);
    *(u32x4_t*)dst = v;
}
// async global->LDS, 16B/lane; LDS dest = wave-uniform base + lane*16
__device__ __forceinline__ void async16(const unsigned short* g, unsigned short* l) {
    __builtin_amdgcn_global_load_lds(
        (const unsigned int __attribute__((address_space(1)))*)g,
        (unsigned int __attribute__((address_space(3)))*)l,
        16, 0, 0);
}

// ---------------- zero-init metadata ----------------
__global__ void init_kernel(int* __restrict__ meta) {
    int i = threadIdx.x;
    if (i < 32) meta[i] = 0;
}

__global__ void noop_kernel() {}

// ---------------- Router (fp32): logits->softmax->top2 ----------------
__global__ void router_kernel(const float* __restrict__ x,
                              const float* __restrict__ cw,
                              const float* __restrict__ bias,
                              int* __restrict__ counts,
                              int* __restrict__ tok_e,
                              float* __restrict__ tok_w,
                              float* __restrict__ zero_w) {
    const int token = blockIdx.x;
    const int ln = threadIdx.x;  // 0..63
    const float* xr = x + (size_t)token * HDIM;
    float acc[NTOT];
#pragma unroll
    for (int e = 0; e < NTOT; ++e) acc[e] = 0.f;
    for (int h0 = ln * 4; h0 < HDIM; h0 += 256) {
        f32x4_t xv = *(const f32x4_t*)(xr + h0);
#pragma unroll
        for (int e = 0; e < NTOT; ++e) {
            f32x4_t wv = *(const f32x4_t*)(cw + e * HDIM + h0);
            acc[e] += xv[0] * wv[0] + xv[1] * wv[1] + xv[2] * wv[2] + xv[3] * wv[3];
        }
    }
#pragma unroll
    for (int e = 0; e < NTOT; ++e) {
        float v = acc[e];
#pragma unroll
        for (int s = 32; s > 0; s >>= 1) v += __shfl_xor(v, s, 64);
        acc[e] = v;
    }
    if (ln == 0) {
        float mx = acc[0];
#pragma unroll
        for (int e = 1; e < NTOT; ++e) mx = fmaxf(mx, acc[e]);
        float p[NTOT];
        float sum = 0.f;
#pragma unroll
        for (int e = 0; e < NTOT; ++e) { p[e] = __expf(acc[e] - mx); sum += p[e]; }
        float inv = 1.f / sum;
#pragma unroll
        for (int e = 0; e < NTOT; ++e) p[e] *= inv;
        float b[NTOT];
#pragma unroll
        for (int e = 0; e < NTOT; ++e) b[e] = p[e] + bias[e];
        int i0 = 0; float v0 = b[0];
#pragma unroll
        for (int e = 1; e < NTOT; ++e) if (b[e] > v0) { v0 = b[e]; i0 = e; }
        int i1 = -1; float v1 = -3.0e38f;
#pragma unroll
        for (int e = 0; e < NTOT; ++e) if (e != i0 && b[e] > v1) { v1 = b[e]; i1 = e; }
        if (i1 < 0) i1 = (i0 == 0) ? 1 : 0;  // defensive
        float w0 = p[i0] * 1.5f, w1 = p[i1] * 1.5f;
        tok_e[2 * token] = i0; tok_e[2 * token + 1] = i1;
        tok_w[2 * token] = w0; tok_w[2 * token + 1] = w1;
        float zw = 0.f;
        if (i0 >= NEXP) zw += w0; else atomicAdd(&counts[i0], 1);
        if (i1 >= NEXP) zw += w1; else atomicAdd(&counts[i1], 1);
        zero_w[token] = zw;
    }
}

// ---------------- prefix scan over 8 experts ----------------
__global__ void scan_kernel(const int* __restrict__ counts, int* __restrict__ offs) {
    if (threadIdx.x == 0 && blockIdx.x == 0) {
        int a = 0;
        for (int e = 0; e < NEXP; ++e) {
            offs[e] = a;
            int c = counts[e];
            if (c < 0) c = 0;
            if (c > T_TOKENS) c = T_TOKENS;
            a += c;
        }
        if (a > 2 * T_TOKENS) a = 2 * T_TOKENS;
        offs[NEXP] = a;
    }
}

// ---------------- place tokens into per-expert contiguous lists ----------------
__global__ void place_kernel(const int* __restrict__ tok_e, const float* __restrict__ tok_w,
                             const int* __restrict__ offs, int* __restrict__ fill,
                             int* __restrict__ token_list, float* __restrict__ slot_w,
                             int* __restrict__ map) {
    int token = blockIdx.x * blockDim.x + threadIdx.x;
    if (token >= T_TOKENS) return;
#pragma unroll
    for (int j = 0; j < 2; ++j) {
        int e = tok_e[2 * token + j];
        int m = -1;
        if (e >= 0 && e < NEXP) {
            int pos = atomicAdd(&fill[e], 1);
            int slot = offs[e] + pos;
            if (slot >= 0 && slot < 2 * T_TOKENS) {
                token_list[slot] = token;
                slot_w[slot] = tok_w[2 * token + j];
                m = slot;
            }
        }
        map[2 * token + j] = m;
    }
}

// ---------------- GEMM1: 64x128 tile, BK=32, double-buffered LDS ----------------
// act[slot, i] = silu(x@gate^T) * (x@up^T) * slot_w
__launch_bounds__(256, 2)
__global__ void gemm1_kernel(const float* __restrict__ x,
                             const float* __restrict__ gate_w,
                             const float* __restrict__ up_w,
                             const int* __restrict__ offs,
                             const int* __restrict__ token_list,
                             const float* __restrict__ slot_w,
                             unsigned short* __restrict__ act) {
    const int e = blockIdx.z;
    const int off = offs[e];
    int Me = offs[e + 1] - off;
    if (Me < 0) Me = 0;
    if (Me > T_TOKENS) Me = T_TOKENS;
    const int m0 = blockIdx.y * 64;
    if (m0 >= Me) return;
    const int n0 = blockIdx.x * 128;

    __shared__ __align__(16) unsigned short As[2][64][32];    // 8 KB
    __shared__ __align__(16) unsigned short Gs[2][128][32];   // 16 KB
    __shared__ __align__(16) unsigned short Us[2][128][32];   // 16 KB

    const int tid = threadIdx.x;
    const int arow = tid >> 2;         // 0..63
    const int acol = (tid & 3) * 8;    // 0,8,16,24

    int tr = m0 + arow; if (tr >= Me) tr = Me - 1;
    int tok = token_list[off + tr];
    if (tok < 0 || tok >= T_TOKENS) tok = 0;
    const float* aA = x + (size_t)tok * HDIM + acol;
    const float* gb = gate_w + (size_t)e * IDIM * HDIM;
    const float* ub = up_w + (size_t)e * IDIM * HDIM;
    const float* aG0 = gb + (size_t)(n0 + arow) * HDIM + acol;
    const float* aG1 = gb + (size_t)(n0 + 64 + arow) * HDIM + acol;
    const float* aU0 = ub + (size_t)(n0 + arow) * HDIM + acol;
    const float* aU1 = ub + (size_t)(n0 + 64 + arow) * HDIM + acol;

    const int wv = tid >> 6, ln = tid & 63;
    const int fr = ln & 15, fk = (ln >> 4) * 8;

    f32x4_t accg[4][2] = {};
    f32x4_t accu[4][2] = {};

    auto stage = [&](int k, int b) {
        const int kc = k * 32;
        f32x4_t a0 = *(const f32x4_t*)(aA + kc);
        f32x4_t a1 = *(const f32x4_t*)(aA + kc + 4);
        f32x4_t g00 = *(const f32x4_t*)(aG0 + kc);
        f32x4_t g01 = *(const f32x4_t*)(aG0 + kc + 4);
        f32x4_t g10 = *(const f32x4_t*)(aG1 + kc);
        f32x4_t g11 = *(const f32x4_t*)(aG1 + kc + 4);
        f32x4_t u00 = *(const f32x4_t*)(aU0 + kc);
        f32x4_t u01 = *(const f32x4_t*)(aU0 + kc + 4);
        f32x4_t u10 = *(const f32x4_t*)(aU1 + kc);
        f32x4_t u11 = *(const f32x4_t*)(aU1 + kc + 4);
        pack8(a0, a1, &As[b][arow][acol]);
        pack8(g00, g01, &Gs[b][arow][acol]);
        pack8(g10, g11, &Gs[b][64 + arow][acol]);
        pack8(u00, u01, &Us[b][arow][acol]);
        pack8(u10, u11, &Us[b][64 + arow][acol]);
    };

    stage(0, 0);
    __syncthreads();
    for (int k = 0; k < HDIM / 32; ++k) {
        const int b = k & 1;
        if (k < HDIM / 32 - 1) stage(k + 1, b ^ 1);
        bf16x8_t af[4], gf[2], uf[2];
#pragma unroll
        for (int t = 0; t < 4; ++t) af[t] = *(const bf16x8_t*)&As[b][t * 16 + fr][fk];
#pragma unroll
        for (int t = 0; t < 2; ++t) {
            gf[t] = *(const bf16x8_t*)&Gs[b][wv * 32 + t * 16 + fr][fk];
            uf[t] = *(const bf16x8_t*)&Us[b][wv * 32 + t * 16 + fr][fk];
        }
#pragma unroll
        for (int mt = 0; mt < 4; ++mt)
#pragma unroll
            for (int nt = 0; nt < 2; ++nt) {
                accg[mt][nt] = __builtin_amdgcn_mfma_f32_16x16x32_bf16(af[mt], gf[nt], accg[mt][nt], 0, 0, 0);
                accu[mt][nt] = __builtin_amdgcn_mfma_f32_16x16x32_bf16(af[mt], uf[nt], accu[mt][nt], 0, 0, 0);
            }
        __syncthreads();
    }

#pragma unroll
    for (int mt = 0; mt < 4; ++mt) {
#pragma unroll
        for (int r = 0; r < 4; ++r) {
            int rloc = mt * 16 + (ln >> 4) * 4 + r;
            int grow = m0 + rloc;
            if (grow < Me) {
                float w = slot_w[off + grow];
                size_t rb = (size_t)(off + grow) * IDIM + n0 + wv * 32;
#pragma unroll
                for (int nt = 0; nt < 2; ++nt) {
                    float g = accg[mt][nt][r];
                    float u = accu[mt][nt][r];
                    float s = g / (1.f + __expf(-g));
                    act[rb + nt * 16 + fr] = f2bf(s * u * w);
                }
            }
        }
    }
}

// ---------------- GEMM2: 64x128 tile, BK=32, dbuf; A=bf16 async16, B=fp32 cvt ----------------
__launch_bounds__(256, 2)
__global__ void gemm2_kernel(const unsigned short* __restrict__ act,
                             const float* __restrict__ dwn,
                             const int* __restrict__ offs,
                             unsigned short* __restrict__ dout) {
    const int e = blockIdx.z;
    const int off = offs[e];
    int Me = offs[e + 1] - off;
    if (Me < 0) Me = 0;
    if (Me > T_TOKENS) Me = T_TOKENS;
    const int m0 = blockIdx.y * 64;
    if (m0 >= Me) return;
    const int n0 = blockIdx.x * 128;

    __shared__ __align__(16) unsigned short As[2][64][32];    // 8 KB
    __shared__ __align__(16) unsigned short Bs[2][128][32];   // 16 KB

    const int tid = threadIdx.x;
    const int wv = tid >> 6, ln = tid & 63;

    // A async16: wave wv stages rows [wv*16, wv*16+16), lane ln -> row wv*16+(ln>>2), col (ln&3)*8
    const int sr = wv * 16 + (ln >> 2);
    const int sc = (ln & 3) * 8;
    int ar = off + m0 + sr; if (ar >= MAX_SLOTS) ar = MAX_SLOTS - 1;
    const unsigned short* aA = act + (size_t)ar * IDIM + sc;
    unsigned short* lA0 = &As[0][wv * 16][0];
    unsigned short* lA1 = &As[1][wv * 16][0];

    // B cvt staging: thread handles rows brow, 64+brow
    const int brow = tid >> 2;
    const int bcol = (tid & 3) * 8;
    const float* bb = dwn + (size_t)e * HDIM * IDIM;
    const float* aB0 = bb + (size_t)(n0 + brow) * IDIM + bcol;
    const float* aB1 = bb + (size_t)(n0 + 64 + brow) * IDIM + bcol;

    const int fr = ln & 15, fk = (ln >> 4) * 8;

    f32x4_t acc[4][2] = {};

    auto stage = [&](int k, int b) {
        const int kc = k * 32;
        async16(aA + kc, b ? lA1 : lA0);
        f32x4_t b00 = *(const f32x4_t*)(aB0 + kc);
        f32x4_t b01 = *(const f32x4_t*)(aB0 + kc + 4);
        f32x4_t b10 = *(const f32x4_t*)(aB1 + kc);
        f32x4_t b11 = *(const f32x4_t*)(aB1 + kc + 4);
        pack8(b00, b01, &Bs[b][brow][bcol]);
        pack8(b10, b11, &Bs[b][64 + brow][bcol]);
    };

    stage(0, 0);
    __syncthreads();
    for (int k = 0; k < IDIM / 32; ++k) {
        const int b = k & 1;
        if (k < IDIM / 32 - 1) stage(k + 1, b ^ 1);
        bf16x8_t af[4], bf[2];
#pragma unroll
        for (int t = 0; t < 4; ++t) af[t] = *(const bf16x8_t*)&As[b][t * 16 + fr][fk];
#pragma unroll
        for (int t = 0; t < 2; ++t) bf[t] = *(const bf16x8_t*)&Bs[b][wv * 32 + t * 16 + fr][fk];
#pragma unroll
        for (int mt = 0; mt < 4; ++mt)
#pragma unroll
            for (int nt = 0; nt < 2; ++nt)
                acc[mt][nt] = __builtin_amdgcn_mfma_f32_16x16x32_bf16(af[mt], bf[nt], acc[mt][nt], 0, 0, 0);
        __syncthreads();
    }

#pragma unroll
    for (int mt = 0; mt < 4; ++mt) {
#pragma unroll
        for (int r = 0; r < 4; ++r) {
            int rloc = mt * 16 + (ln >> 4) * 4 + r;
            int grow = m0 + rloc;
            if (grow < Me) {
                size_t rb = (size_t)(off + grow) * HDIM + n0 + wv * 32;
#pragma unroll
                for (int nt = 0; nt < 2; ++nt)
                    dout[rb + nt * 16 + fr] = f2bf(acc[mt][nt][r]);
            }
        }
    }
}

// ---------------- finalize: out(fp32) = sum(slot rows bf16) + zero_w * x(fp32) ----------------
__global__ void finalize_kernel(const float* __restrict__ x,
                                const unsigned short* __restrict__ dout,
                                const int* __restrict__ map,
                                const float* __restrict__ zero_w,
                                float* __restrict__ out) {
    int gid = blockIdx.x * blockDim.x + threadIdx.x;  // T*H/8 total
    int token = gid >> 8;
    int hg = (gid & 255) * 8;
    int s0 = map[2 * token], s1 = map[2 * token + 1];
    float zw = zero_w[token];
    size_t base = (size_t)token * HDIM + hg;
    f32x4_t x0 = *(const f32x4_t*)(x + base);
    f32x4_t x1 = *(const f32x4_t*)(x + base + 4);
    float o[8];
#pragma unroll
    for (int j = 0; j < 4; ++j) { o[j] = zw * x0[j]; o[4 + j] = zw * x1[j]; }
    if (s0 >= 0 && s0 < 2 * T_TOKENS) {
        u16x8_t d = *(const u16x8_t*)(dout + (size_t)s0 * HDIM + hg);
#pragma unroll
        for (int j = 0; j < 8; ++j) o[j] += bfu2f(d[j]);
    }
    if (s1 >= 0 && s1 < 2 * T_TOKENS) {
        u16x8_t d = *(const u16x8_t*)(dout + (size_t)s1 * HDIM + hg);
#pragma unroll
        for (int j = 0; j < 8; ++j) o[j] += bfu2f(d[j]);
    }
    f32x4_t o0, o1;
#pragma unroll
    for (int j = 0; j < 4; ++j) { o0[j] = o[j]; o1[j] = o[4 + j]; }
    *(f32x4_t*)(out + base) = o0;
    *(f32x4_t*)(out + base + 4) = o1;
}

// ---------------- launch ----------------
extern "C" void kernel_launch(void* const* d_in, const int* in_sizes, int n_in,
                              void* d_out, int out_size, void* d_ws, size_t ws_size,
                              hipStream_t stream) {
    const float* x = (const float*)d_in[0];
    const float* cw = (const float*)d_in[1];
    const float* bias = (const float*)d_in[2];
    const float* gw = (const float*)d_in[3];
    const float* uw = (const float*)d_in[4];
    const float* dw = (const float*)d_in[5];
    float* out = (float*)d_out;

    char* ws = (char*)d_ws;
    int* counts = (int*)(ws + 0);                 // 32 B
    int* fill = (int*)(ws + 32);                  // 32 B
    int* offs = (int*)(ws + 64);                  // 64 B (9 ints)
    int* tok_e = (int*)(ws + 128);                // 32768
    float* tok_w = (float*)(ws + 32896);          // 32768
    float* zero_w = (float*)(ws + 65664);         // 16384
    int* map = (int*)(ws + 82048);                // 32768
    int* token_list = (int*)(ws + 114816);        // 33280
    float* slot_w = (float*)(ws + 148096);        // 33280
    unsigned short* act = (unsigned short*)(ws + 181504);             // 8320*1024*2
    unsigned short* dout = (unsigned short*)(ws + 181504 + 17039360); // 8320*2048*2
    const size_t needed = 181504ull + 17039360ull + 34078720ull;
    if (ws_size < needed) {
        noop_kernel<<<1, 64, 0, stream>>>();
        return;
    }

    init_kernel<<<1, 64, 0, stream>>>((int*)ws);

    router_kernel<<<T_TOKENS, 64, 0, stream>>>(x, cw, bias, counts, tok_e, tok_w, zero_w);
    scan_kernel<<<1, 64, 0, stream>>>(counts, offs);
    place_kernel<<<(T_TOKENS + 255) / 256, 256, 0, stream>>>(tok_e, tok_w, offs, fill,
                                                             token_list, slot_w, map);
    gemm1_kernel<<<dim3(IDIM / 128, T_TOKENS / 64, NEXP), 256, 0, stream>>>(
        x, gw, uw, offs, token_list, slot_w, act);
    gemm2_kernel<<<dim3(HDIM / 128, T_TOKENS / 64, NEXP), 256, 0, stream>>>(
        act, dw, offs, dout);
    finalize_kernel<<<(T_TOKENS * HDIM / 8 + 255) / 256, 256, 0, stream>>>(x, dout, map,
                                                                           zero_w, out);
}

// Round 6
// 523.573 us; speedup vs baseline: 1.0215x; 1.0215x over previous
//
#include <hip/hip_runtime.h>
#include <cstdint>

#define T_TOKENS 4096
#define HDIM 2048
#define IDIM 1024
#define NEXP 8
#define NTOT 12
#define MAX_SLOTS 8320   // 8192 + 128 pad for tile overshoot reads

typedef __bf16 bf16x8_t __attribute__((ext_vector_type(8)));
typedef float f32x4_t __attribute__((ext_vector_type(4)));
typedef unsigned short u16x8_t __attribute__((ext_vector_type(8)));
typedef unsigned int u32x4_t __attribute__((ext_vector_type(4)));

__device__ __forceinline__ unsigned short f2bf(float f) {
    unsigned int u = __builtin_bit_cast(unsigned int, f);
    u += 0x7fffu + ((u >> 16) & 1u);
    return (unsigned short)(u >> 16);
}
__device__ __forceinline__ float bfu2f(unsigned short u) {
    unsigned int v = ((unsigned int)u) << 16;
    return __builtin_bit_cast(float, v);
}
__device__ __forceinline__ unsigned int pk2(float a, float b) {
    return (unsigned int)f2bf(a) | ((unsigned int)f2bf(b) << 16);
}
// pack 8 fp32 (2x f32x4) -> 8 bf16, one ds_write_b128
__device__ __forceinline__ void pack8(f32x4_t f0, f32x4_t f1, unsigned short* dst) {
    u32x4_t v;
    v[0] = pk2(f0[0], f0[1]);
    v[1] = pk2(f0[2], f0[3]);
    v[2] = pk2(f1[0], f1[1]);
    v[3] = pk2(f1[2], f1[3]);
    *(u32x4_t*)dst = v;
}
// async global->LDS, 16B/lane; LDS dest = wave-uniform base + lane*16
__device__ __forceinline__ void async16(const unsigned short* g, unsigned short* l) {
    __builtin_amdgcn_global_load_lds(
        (const unsigned int __attribute__((address_space(1)))*)g,
        (unsigned int __attribute__((address_space(3)))*)l,
        16, 0, 0);
}

// ---------------- zero-init metadata ----------------
__global__ void init_kernel(int* __restrict__ meta) {
    int i = threadIdx.x;
    if (i < 32) meta[i] = 0;
}

__global__ void noop_kernel() {}

// ---------------- Router (fp32): logits->softmax->top2 ----------------
__global__ void router_kernel(const float* __restrict__ x,
                              const float* __restrict__ cw,
                              const float* __restrict__ bias,
                              int* __restrict__ counts,
                              int* __restrict__ tok_e,
                              float* __restrict__ tok_w,
                              float* __restrict__ zero_w) {
    const int token = blockIdx.x;
    const int ln = threadIdx.x;  // 0..63
    const float* xr = x + (size_t)token * HDIM;
    float acc[NTOT];
#pragma unroll
    for (int e = 0; e < NTOT; ++e) acc[e] = 0.f;
    for (int h0 = ln * 4; h0 < HDIM; h0 += 256) {
        f32x4_t xv = *(const f32x4_t*)(xr + h0);
#pragma unroll
        for (int e = 0; e < NTOT; ++e) {
            f32x4_t wv = *(const f32x4_t*)(cw + e * HDIM + h0);
            acc[e] += xv[0] * wv[0] + xv[1] * wv[1] + xv[2] * wv[2] + xv[3] * wv[3];
        }
    }
#pragma unroll
    for (int e = 0; e < NTOT; ++e) {
        float v = acc[e];
#pragma unroll
        for (int s = 32; s > 0; s >>= 1) v += __shfl_xor(v, s, 64);
        acc[e] = v;
    }
    if (ln == 0) {
        float mx = acc[0];
#pragma unroll
        for (int e = 1; e < NTOT; ++e) mx = fmaxf(mx, acc[e]);
        float p[NTOT];
        float sum = 0.f;
#pragma unroll
        for (int e = 0; e < NTOT; ++e) { p[e] = __expf(acc[e] - mx); sum += p[e]; }
        float inv = 1.f / sum;
#pragma unroll
        for (int e = 0; e < NTOT; ++e) p[e] *= inv;
        float b[NTOT];
#pragma unroll
        for (int e = 0; e < NTOT; ++e) b[e] = p[e] + bias[e];
        int i0 = 0; float v0 = b[0];
#pragma unroll
        for (int e = 1; e < NTOT; ++e) if (b[e] > v0) { v0 = b[e]; i0 = e; }
        int i1 = -1; float v1 = -3.0e38f;
#pragma unroll
        for (int e = 0; e < NTOT; ++e) if (e != i0 && b[e] > v1) { v1 = b[e]; i1 = e; }
        if (i1 < 0) i1 = (i0 == 0) ? 1 : 0;  // defensive
        float w0 = p[i0] * 1.5f, w1 = p[i1] * 1.5f;
        tok_e[2 * token] = i0; tok_e[2 * token + 1] = i1;
        tok_w[2 * token] = w0; tok_w[2 * token + 1] = w1;
        float zw = 0.f;
        if (i0 >= NEXP) zw += w0; else atomicAdd(&counts[i0], 1);
        if (i1 >= NEXP) zw += w1; else atomicAdd(&counts[i1], 1);
        zero_w[token] = zw;
    }
}

// ---------------- prefix scan over 8 experts ----------------
__global__ void scan_kernel(const int* __restrict__ counts, int* __restrict__ offs) {
    if (threadIdx.x == 0 && blockIdx.x == 0) {
        int a = 0;
        for (int e = 0; e < NEXP; ++e) {
            offs[e] = a;
            int c = counts[e];
            if (c < 0) c = 0;
            if (c > T_TOKENS) c = T_TOKENS;
            a += c;
        }
        if (a > 2 * T_TOKENS) a = 2 * T_TOKENS;
        offs[NEXP] = a;
    }
}

// ---------------- place tokens into per-expert contiguous lists ----------------
__global__ void place_kernel(const int* __restrict__ tok_e, const float* __restrict__ tok_w,
                             const int* __restrict__ offs, int* __restrict__ fill,
                             int* __restrict__ token_list, float* __restrict__ slot_w,
                             int* __restrict__ map) {
    int token = blockIdx.x * blockDim.x + threadIdx.x;
    if (token >= T_TOKENS) return;
#pragma unroll
    for (int j = 0; j < 2; ++j) {
        int e = tok_e[2 * token + j];
        int m = -1;
        if (e >= 0 && e < NEXP) {
            int pos = atomicAdd(&fill[e], 1);
            int slot = offs[e] + pos;
            if (slot >= 0 && slot < 2 * T_TOKENS) {
                token_list[slot] = token;
                slot_w[slot] = tok_w[2 * token + j];
                m = slot;
            }
        }
        map[2 * token + j] = m;
    }
}

// ---------------- GEMM1: 64x128 tile, BK=32, depth-2 register-prefetch pipeline ----------------
// act[slot, i] = silu(x@gate^T) * (x@up^T) * slot_w
__launch_bounds__(256, 2)
__global__ void gemm1_kernel(const float* __restrict__ x,
                             const float* __restrict__ gate_w,
                             const float* __restrict__ up_w,
                             const int* __restrict__ offs,
                             const int* __restrict__ token_list,
                             const float* __restrict__ slot_w,
                             unsigned short* __restrict__ act) {
    const int e = blockIdx.z;
    const int off = offs[e];
    int Me = offs[e + 1] - off;
    if (Me < 0) Me = 0;
    if (Me > T_TOKENS) Me = T_TOKENS;
    const int m0 = blockIdx.y * 64;
    if (m0 >= Me) return;
    const int n0 = blockIdx.x * 128;

    __shared__ __align__(16) unsigned short As[2][64][32];    // 8 KB
    __shared__ __align__(16) unsigned short Gs[2][128][32];   // 16 KB
    __shared__ __align__(16) unsigned short Us[2][128][32];   // 16 KB

    const int tid = threadIdx.x;
    const int arow = tid >> 2;         // 0..63
    const int acol = (tid & 3) * 8;    // 0,8,16,24

    int tr = m0 + arow; if (tr >= Me) tr = Me - 1;
    int tok = token_list[off + tr];
    if (tok < 0 || tok >= T_TOKENS) tok = 0;
    const float* aA = x + (size_t)tok * HDIM + acol;
    const float* gb = gate_w + (size_t)e * IDIM * HDIM;
    const float* ub = up_w + (size_t)e * IDIM * HDIM;
    const float* aG0 = gb + (size_t)(n0 + arow) * HDIM + acol;
    const float* aG1 = gb + (size_t)(n0 + 64 + arow) * HDIM + acol;
    const float* aU0 = ub + (size_t)(n0 + arow) * HDIM + acol;
    const float* aU1 = ub + (size_t)(n0 + 64 + arow) * HDIM + acol;

    const int wv = tid >> 6, ln = tid & 63;
    const int fr = ln & 15, fk = (ln >> 4) * 8;

    f32x4_t accg[4][2] = {};
    f32x4_t accu[4][2] = {};

    f32x4_t rg[10];
    auto gload = [&](int k) {
        const int kc = k * 32;
        rg[0] = *(const f32x4_t*)(aA + kc);
        rg[1] = *(const f32x4_t*)(aA + kc + 4);
        rg[2] = *(const f32x4_t*)(aG0 + kc);
        rg[3] = *(const f32x4_t*)(aG0 + kc + 4);
        rg[4] = *(const f32x4_t*)(aG1 + kc);
        rg[5] = *(const f32x4_t*)(aG1 + kc + 4);
        rg[6] = *(const f32x4_t*)(aU0 + kc);
        rg[7] = *(const f32x4_t*)(aU0 + kc + 4);
        rg[8] = *(const f32x4_t*)(aU1 + kc);
        rg[9] = *(const f32x4_t*)(aU1 + kc + 4);
    };
    auto lwrite = [&](int b) {
        pack8(rg[0], rg[1], &As[b][arow][acol]);
        pack8(rg[2], rg[3], &Gs[b][arow][acol]);
        pack8(rg[4], rg[5], &Gs[b][64 + arow][acol]);
        pack8(rg[6], rg[7], &Us[b][arow][acol]);
        pack8(rg[8], rg[9], &Us[b][64 + arow][acol]);
    };

    const int KIT = HDIM / 32;
    gload(0);
    lwrite(0);
    gload(1);          // in flight across the barrier + first MFMA block
    __syncthreads();

    for (int k = 0; k < KIT; ++k) {
        const int b = k & 1;
        bf16x8_t af[4], gf[2], uf[2];
#pragma unroll
        for (int t = 0; t < 4; ++t) af[t] = *(const bf16x8_t*)&As[b][t * 16 + fr][fk];
#pragma unroll
        for (int t = 0; t < 2; ++t) {
            gf[t] = *(const bf16x8_t*)&Gs[b][wv * 32 + t * 16 + fr][fk];
            uf[t] = *(const bf16x8_t*)&Us[b][wv * 32 + t * 16 + fr][fk];
        }
#pragma unroll
        for (int mt = 0; mt < 4; ++mt)
#pragma unroll
            for (int nt = 0; nt < 2; ++nt) {
                accg[mt][nt] = __builtin_amdgcn_mfma_f32_16x16x32_bf16(af[mt], gf[nt], accg[mt][nt], 0, 0, 0);
                accu[mt][nt] = __builtin_amdgcn_mfma_f32_16x16x32_bf16(af[mt], uf[nt], accu[mt][nt], 0, 0, 0);
            }
        if (k + 1 < KIT) {
            lwrite(b ^ 1);             // consumes rg loaded one iteration ago
            if (k + 2 < KIT) gload(k + 2);
        }
        __syncthreads();
    }

#pragma unroll
    for (int mt = 0; mt < 4; ++mt) {
#pragma unroll
        for (int r = 0; r < 4; ++r) {
            int rloc = mt * 16 + (ln >> 4) * 4 + r;
            int grow = m0 + rloc;
            if (grow < Me) {
                float w = slot_w[off + grow];
                size_t rb = (size_t)(off + grow) * IDIM + n0 + wv * 32;
#pragma unroll
                for (int nt = 0; nt < 2; ++nt) {
                    float g = accg[mt][nt][r];
                    float u = accu[mt][nt][r];
                    float s = g / (1.f + __expf(-g));
                    act[rb + nt * 16 + fr] = f2bf(s * u * w);
                }
            }
        }
    }
}

// ---------------- GEMM2: 64x128 tile, BK=32, pipelined; A=bf16 async16, B=fp32 prefetch ----------------
__launch_bounds__(256, 2)
__global__ void gemm2_kernel(const unsigned short* __restrict__ act,
                             const float* __restrict__ dwn,
                             const int* __restrict__ offs,
                             unsigned short* __restrict__ dout) {
    const int e = blockIdx.z;
    const int off = offs[e];
    int Me = offs[e + 1] - off;
    if (Me < 0) Me = 0;
    if (Me > T_TOKENS) Me = T_TOKENS;
    const int m0 = blockIdx.y * 64;
    if (m0 >= Me) return;
    const int n0 = blockIdx.x * 128;

    __shared__ __align__(16) unsigned short As[2][64][32];    // 8 KB
    __shared__ __align__(16) unsigned short Bs[2][128][32];   // 16 KB

    const int tid = threadIdx.x;
    const int wv = tid >> 6, ln = tid & 63;

    // A async16: wave wv stages rows [wv*16, wv*16+16); lane ln -> row wv*16+(ln>>2), col (ln&3)*8
    const int sr = wv * 16 + (ln >> 2);
    const int sc = (ln & 3) * 8;
    int ar = off + m0 + sr; if (ar >= MAX_SLOTS) ar = MAX_SLOTS - 1;
    const unsigned short* aA = act + (size_t)ar * IDIM + sc;
    unsigned short* lA0 = &As[0][wv * 16][0];
    unsigned short* lA1 = &As[1][wv * 16][0];

    // B prefetch staging: thread covers rows brow and 64+brow, 8 cols at bcol
    const int brow = tid >> 2;
    const int bcol = (tid & 3) * 8;
    const float* bb = dwn + (size_t)e * HDIM * IDIM;
    const float* aB0 = bb + (size_t)(n0 + brow) * IDIM + bcol;
    const float* aB1 = bb + (size_t)(n0 + 64 + brow) * IDIM + bcol;

    const int fr = ln & 15, fk = (ln >> 4) * 8;

    f32x4_t acc[4][2] = {};

    f32x4_t rb[4];
    auto bload = [&](int k) {
        const int kc = k * 32;
        rb[0] = *(const f32x4_t*)(aB0 + kc);
        rb[1] = *(const f32x4_t*)(aB0 + kc + 4);
        rb[2] = *(const f32x4_t*)(aB1 + kc);
        rb[3] = *(const f32x4_t*)(aB1 + kc + 4);
    };
    auto bwrite = [&](int b) {
        pack8(rb[0], rb[1], &Bs[b][brow][bcol]);
        pack8(rb[2], rb[3], &Bs[b][64 + brow][bcol]);
    };

    const int KIT = IDIM / 32;
    async16(aA + 0, lA0);
    bload(0);
    bwrite(0);
    bload(1);
    __syncthreads();

    for (int k = 0; k < KIT; ++k) {
        const int b = k & 1;
        bf16x8_t af[4], bf[2];
#pragma unroll
        for (int t = 0; t < 4; ++t) af[t] = *(const bf16x8_t*)&As[b][t * 16 + fr][fk];
#pragma unroll
        for (int t = 0; t < 2; ++t) bf[t] = *(const bf16x8_t*)&Bs[b][wv * 32 + t * 16 + fr][fk];
#pragma unroll
        for (int mt = 0; mt < 4; ++mt)
#pragma unroll
            for (int nt = 0; nt < 2; ++nt)
                acc[mt][nt] = __builtin_amdgcn_mfma_f32_16x16x32_bf16(af[mt], bf[nt], acc[mt][nt], 0, 0, 0);
        if (k + 1 < KIT) {
            async16(aA + (k + 1) * 32, b ? lA0 : lA1);  // prep buffer b^1
            bwrite(b ^ 1);                               // consumes rb from one iter ago
            if (k + 2 < KIT) bload(k + 2);
        }
        __syncthreads();
    }

#pragma unroll
    for (int mt = 0; mt < 4; ++mt) {
#pragma unroll
        for (int r = 0; r < 4; ++r) {
            int rloc = mt * 16 + (ln >> 4) * 4 + r;
            int grow = m0 + rloc;
            if (grow < Me) {
                size_t rb2 = (size_t)(off + grow) * HDIM + n0 + wv * 32;
#pragma unroll
                for (int nt = 0; nt < 2; ++nt)
                    dout[rb2 + nt * 16 + fr] = f2bf(acc[mt][nt][r]);
            }
        }
    }
}

// ---------------- finalize: out(fp32) = sum(slot rows bf16) + zero_w * x(fp32) ----------------
__global__ void finalize_kernel(const float* __restrict__ x,
                                const unsigned short* __restrict__ dout,
                                const int* __restrict__ map,
                                const float* __restrict__ zero_w,
                                float* __restrict__ out) {
    int gid = blockIdx.x * blockDim.x + threadIdx.x;  // T*H/8 total
    int token = gid >> 8;
    int hg = (gid & 255) * 8;
    int s0 = map[2 * token], s1 = map[2 * token + 1];
    float zw = zero_w[token];
    size_t base = (size_t)token * HDIM + hg;
    f32x4_t x0 = *(const f32x4_t*)(x + base);
    f32x4_t x1 = *(const f32x4_t*)(x + base + 4);
    float o[8];
#pragma unroll
    for (int j = 0; j < 4; ++j) { o[j] = zw * x0[j]; o[4 + j] = zw * x1[j]; }
    if (s0 >= 0 && s0 < 2 * T_TOKENS) {
        u16x8_t d = *(const u16x8_t*)(dout + (size_t)s0 * HDIM + hg);
#pragma unroll
        for (int j = 0; j < 8; ++j) o[j] += bfu2f(d[j]);
    }
    if (s1 >= 0 && s1 < 2 * T_TOKENS) {
        u16x8_t d = *(const u16x8_t*)(dout + (size_t)s1 * HDIM + hg);
#pragma unroll
        for (int j = 0; j < 8; ++j) o[j] += bfu2f(d[j]);
    }
    f32x4_t o0, o1;
#pragma unroll
    for (int j = 0; j < 4; ++j) { o0[j] = o[j]; o1[j] = o[4 + j]; }
    *(f32x4_t*)(out + base) = o0;
    *(f32x4_t*)(out + base + 4) = o1;
}

// ---------------- launch ----------------
extern "C" void kernel_launch(void* const* d_in, const int* in_sizes, int n_in,
                              void* d_out, int out_size, void* d_ws, size_t ws_size,
                              hipStream_t stream) {
    const float* x = (const float*)d_in[0];
    const float* cw = (const float*)d_in[1];
    const float* bias = (const float*)d_in[2];
    const float* gw = (const float*)d_in[3];
    const float* uw = (const float*)d_in[4];
    const float* dw = (const float*)d_in[5];
    float* out = (float*)d_out;

    char* ws = (char*)d_ws;
    int* counts = (int*)(ws + 0);                 // 32 B
    int* fill = (int*)(ws + 32);                  // 32 B
    int* offs = (int*)(ws + 64);                  // 64 B (9 ints)
    int* tok_e = (int*)(ws + 128);                // 32768
    float* tok_w = (float*)(ws + 32896);          // 32768
    float* zero_w = (float*)(ws + 65664);         // 16384
    int* map = (int*)(ws + 82048);                // 32768
    int* token_list = (int*)(ws + 114816);        // 33280
    float* slot_w = (float*)(ws + 148096);        // 33280
    unsigned short* act = (unsigned short*)(ws + 181504);             // 8320*1024*2
    unsigned short* dout = (unsigned short*)(ws + 181504 + 17039360); // 8320*2048*2
    const size_t needed = 181504ull + 17039360ull + 34078720ull;
    if (ws_size < needed) {
        noop_kernel<<<1, 64, 0, stream>>>();
        return;
    }

    init_kernel<<<1, 64, 0, stream>>>((int*)ws);

    router_kernel<<<T_TOKENS, 64, 0, stream>>>(x, cw, bias, counts, tok_e, tok_w, zero_w);
    scan_kernel<<<1, 64, 0, stream>>>(counts, offs);
    place_kernel<<<(T_TOKENS + 255) / 256, 256, 0, stream>>>(tok_e, tok_w, offs, fill,
                                                             token_list, slot_w, map);
    gemm1_kernel<<<dim3(IDIM / 128, T_TOKENS / 64, NEXP), 256, 0, stream>>>(
        x, gw, uw, offs, token_list, slot_w, act);
    gemm2_kernel<<<dim3(HDIM / 128, T_TOKENS / 64, NEXP), 256, 0, stream>>>(
        act, dw, offs, dout);
    finalize_kernel<<<(T_TOKENS * HDIM / 8 + 255) / 256, 256, 0, stream>>>(x, dout, map,
                                                                           zero_w, out);
}